// Round 6
// baseline (43.042 us; speedup 1.0000x reference)
//
#include <hip/hip_runtime.h>
#include <math.h>

constexpr int NN   = 512;
constexpr int FIN  = 256;
constexpr int FOUT = 128;
constexpr int NBLK2 = 256;   // K2 block count (must equal its grid size)

// ---------------------------------------------------------------------------
// K1: Wh = x@W, u_i = sum_o a_o*Wh[i,o]  (R4's proven kernel) + ctr reset
// 256 blocks x 512 thr, 4 rows/block.
// ---------------------------------------------------------------------------
__global__ __launch_bounds__(512) void wh_u_kernel(const float* __restrict__ x,
                                                   const float* __restrict__ W,
                                                   const float* __restrict__ a_fc,
                                                   float* __restrict__ Wh,
                                                   float* __restrict__ u,
                                                   int* __restrict__ ctr) {
    __shared__ float  xs[4][FIN];
    __shared__ float4 part[4][4][32];
    __shared__ float  upart[8][4];

    const int t  = threadIdx.x;
    const int g0 = blockIdx.x * 4;

    if (blockIdx.x == 0 && t == 0)
        __hip_atomic_store(ctr, 0, __ATOMIC_RELEASE, __HIP_MEMORY_SCOPE_AGENT);

    if (t < 256)
        ((float4*)xs)[t] = ((const float4*)(x + (size_t)g0 * FIN))[t];
    __syncthreads();

    const int rl = t >> 7;         // 0..3
    const int fs = (t >> 5) & 3;   // 0..3
    const int og = t & 31;         // 0..31
    const float* xr = &xs[rl][fs * 64];
    const float4* W4 = (const float4*)W;

    float4 acc = {0.f, 0.f, 0.f, 0.f};
#pragma unroll 8
    for (int f = 0; f < 64; ++f) {
        const float  xv = xr[f];
        const float4 wv = W4[(size_t)(fs * 64 + f) * 32 + og];
        acc.x = fmaf(xv, wv.x, acc.x);
        acc.y = fmaf(xv, wv.y, acc.y);
        acc.z = fmaf(xv, wv.z, acc.z);
        acc.w = fmaf(xv, wv.w, acc.w);
    }
    part[rl][fs][og] = acc;
    __syncthreads();

    if (t < 128) {
        const int crl = t & 3;
        const int cog = t >> 2;
        const float4 s0 = part[crl][0][cog];
        const float4 s1 = part[crl][1][cog];
        const float4 s2 = part[crl][2][cog];
        const float4 s3 = part[crl][3][cog];
        float4 w4;
        w4.x = (s0.x + s1.x) + (s2.x + s3.x);
        w4.y = (s0.y + s1.y) + (s2.y + s3.y);
        w4.z = (s0.z + s1.z) + (s2.z + s3.z);
        w4.w = (s0.w + s1.w) + (s2.w + s3.w);
        ((float4*)(Wh + (size_t)(g0 + crl) * FOUT))[cog] = w4;

        const float4 a4 = ((const float4*)a_fc)[cog];
        float pa = w4.x * a4.x + w4.y * a4.y + w4.z * a4.z + w4.w * a4.w;
#pragma unroll
        for (int off = 32; off >= 4; off >>= 1) pa += __shfl_down(pa, off);
        if ((t & 63) < 4) upart[t >> 6][t & 3] = pa;
    }
    __syncthreads();
    if (t < 4) {
        u[g0 + t] = upart[0][t] + upart[1][t];
    }
}

// ---------------------------------------------------------------------------
// K2: fused e -> global norm (scalar spin-barrier) -> softmax -> PV -> elu
// 256 blocks x 512 thr; block = 4 rows of one batch. e lives in LDS only.
// e-phase: 8 chunks of 64 j-rows staged in LDS with XOR swizzle
// (float4-slot ^ (row&7)) so per-lane-row ds_read_b128 hits the 8cy floor.
// Thread (jj=t&63, oq=t>>6) accumulates o-sub-range for all 4 i's.
// Barrier: atomic partials + counter, consumers re-read via atomic RMW
// (coherent point) -> immune to per-XCD L2 non-coherence; fixed-order sum
// -> deterministic.
// ---------------------------------------------------------------------------
__global__ __launch_bounds__(512) void gat_main_kernel(
        const float* __restrict__ Wh, const float* __restrict__ u,
        const float* __restrict__ a_fc, const int* __restrict__ adj,
        float* __restrict__ out, float* __restrict__ partials,
        int* __restrict__ ctr) {
    __shared__ float whj[64 * 128];      // 32KB, swizzled j-panel chunk
    __shared__ float whi[4 * 128];       // this block's 4 Wh rows
    __shared__ float a4s[128];           // 0.4 * a
    __shared__ float uj6[NN];            // 0.6 * u (whole batch row)
    __shared__ float e_l[4 * NN];        // e, overwritten by p
    __shared__ float parts[8 * 4 * 64];  // e o-partials; reused for PV combine
    __shared__ float red[8];
    __shared__ float scal[8];

    const int t   = threadIdx.x;
    const int bid = blockIdx.x;
    const int b   = bid >> 7;            // 128 blocks per batch
    const int i0  = (bid & 127) * 4;     // row within batch
    const float* whB = Wh + (size_t)b * NN * FOUT;

    // stage block-constant data (synced by first chunk's barrier)
    if (t < 128) {
        ((float4*)whi)[t] =
            ((const float4*)(whB + (size_t)(i0 + (t >> 5)) * FOUT))[t & 31];
    } else if (t < 160) {
        float4 a = ((const float4*)a_fc)[t - 128];
        a.x *= 0.4f; a.y *= 0.4f; a.z *= 0.4f; a.w *= 0.4f;
        ((float4*)a4s)[t - 128] = a;
    } else if (t >= 256 && t < 384) {
        float4 uu = ((const float4*)(u + (size_t)b * NN))[t - 256];
        uu.x *= 0.6f; uu.y *= 0.6f; uu.z *= 0.6f; uu.w *= 0.6f;
        ((float4*)uj6)[t - 256] = uu;
    }

    const int jj = t & 63;
    const int oq = t >> 6;
    float ss = 0.f;

#define EACC(IV, AC)                                              \
    { float s;                                                    \
      s = IV.x + jv.x; AC = fmaf(av.x, fabsf(s), AC);             \
      s = IV.y + jv.y; AC = fmaf(av.y, fabsf(s), AC);             \
      s = IV.z + jv.z; AC = fmaf(av.z, fabsf(s), AC);             \
      s = IV.w + jv.w; AC = fmaf(av.w, fabsf(s), AC); }

    for (int c = 0; c < 8; ++c) {
        // stage 64-row j-panel chunk, swizzled
#pragma unroll
        for (int it = 0; it < 4; ++it) {
            const int f4i = it * 512 + t;
            const int row = f4i >> 5, c4 = f4i & 31;
            const float4 v =
                ((const float4*)(whB + (size_t)(c * 64 + row) * FOUT))[c4];
            *(float4*)&whj[row * 128 + ((c4 ^ (row & 7)) << 2)] = v;
        }
        __syncthreads();

        float ac0 = 0.f, ac1 = 0.f, ac2 = 0.f, ac3 = 0.f;
#pragma unroll
        for (int k = 0; k < 4; ++k) {
            const int ob = oq * 16 + k * 4;
            const float4 jv =
                *(const float4*)&whj[jj * 128 + ((((ob >> 2)) ^ (jj & 7)) << 2)];
            const float4 av = *(const float4*)&a4s[ob];
            float4 iv;
            iv = *(const float4*)&whi[0 * 128 + ob]; EACC(iv, ac0)
            iv = *(const float4*)&whi[1 * 128 + ob]; EACC(iv, ac1)
            iv = *(const float4*)&whi[2 * 128 + ob]; EACC(iv, ac2)
            iv = *(const float4*)&whi[3 * 128 + ob]; EACC(iv, ac3)
        }
        parts[(oq * 4 + 0) * 64 + jj] = ac0;
        parts[(oq * 4 + 1) * 64 + jj] = ac1;
        parts[(oq * 4 + 2) * 64 + jj] = ac2;
        parts[(oq * 4 + 3) * 64 + jj] = ac3;
        __syncthreads();

        if (t < 256) {
            const int i = t >> 6, j2 = t & 63;
            float s4 = 0.f;
#pragma unroll
            for (int q = 0; q < 8; ++q) s4 += parts[(q * 4 + i) * 64 + j2];
            const float ev = s4 + uj6[i0 + i] + uj6[c * 64 + j2];
            e_l[i * NN + c * 64 + j2] = ev;
            ss = fmaf(ev, ev, ss);
        }
        // no extra sync: next chunk's post-stage barrier orders
        // combine-reads(parts) before compute-writes(parts)
    }
#undef EACC

    // ---- block sumsq -> global barrier on scalar partials ----
    float v = ss;
#pragma unroll
    for (int off = 32; off; off >>= 1) v += __shfl_down(v, off);
    if (t < 256 && (t & 63) == 0) red[t >> 6] = v;
    __syncthreads();                                   // S1
    if (t == 0) {
        const float tot = (red[0] + red[1]) + (red[2] + red[3]);
        __hip_atomic_store(&partials[bid], tot, __ATOMIC_RELEASE,
                           __HIP_MEMORY_SCOPE_AGENT);
        __hip_atomic_fetch_add(ctr, 1, __ATOMIC_ACQ_REL,
                               __HIP_MEMORY_SCOPE_AGENT);
        while (__hip_atomic_load(ctr, __ATOMIC_ACQUIRE,
                                 __HIP_MEMORY_SCOPE_AGENT) < NBLK2)
            __builtin_amdgcn_s_sleep(2);
    }
    __syncthreads();                                   // S2

    // coherent re-read of all partials; fixed-order reduce (deterministic)
    float pv = 0.f;
    if (t < 256)
        pv = __hip_atomic_fetch_add(&partials[t], 0.0f, __ATOMIC_RELAXED,
                                    __HIP_MEMORY_SCOPE_AGENT);
#pragma unroll
    for (int off = 32; off; off >>= 1) pv += __shfl_down(pv, off);
    if (t < 256 && (t & 63) == 0) red[t >> 6] = pv;
    __syncthreads();                                   // S3
    const float inv_norm = 1.0f / sqrtf((red[0] + red[1]) + (red[2] + red[3]));

    // ---- softmax: wave-pair per row ----
    const int w  = t >> 6;        // 0..7
    const int r  = w >> 1;        // row 0..3
    const int hf = w & 1;
    const int l  = t & 63;
    const int j4 = hf * 64 + l;   // float4 index in row

    const int4 am =
        ((const int4*)(adj + (size_t)(b * NN + i0 + r) * NN))[j4];
    const float4 e4 = ((const float4*)&e_l[r * NN])[j4];
    const float m0 = am.x ? e4.x * inv_norm : -INFINITY;
    const float m1 = am.y ? e4.y * inv_norm : -INFINITY;
    const float m2 = am.z ? e4.z * inv_norm : -INFINITY;
    const float m3 = am.w ? e4.w * inv_norm : -INFINITY;

    float mx = fmaxf(fmaxf(m0, m1), fmaxf(m2, m3));
#pragma unroll
    for (int off = 32; off; off >>= 1) mx = fmaxf(mx, __shfl_xor(mx, off));
    if (l == 0) red[w] = mx;
    __syncthreads();                                   // S4
    mx = fmaxf(red[2 * r], red[2 * r + 1]);

    float4 p4;
    p4.x = expf(m0 - mx);
    p4.y = expf(m1 - mx);
    p4.z = expf(m2 - mx);
    p4.w = expf(m3 - mx);
    ((float4*)&e_l[r * NN])[j4] = p4;
    float sm = (p4.x + p4.y) + (p4.z + p4.w);
#pragma unroll
    for (int off = 32; off; off >>= 1) sm += __shfl_xor(sm, off);
    if (l == 0) scal[w] = sm;
    __syncthreads();                                   // S5 (p stores visible)

    // ---- PV: thread (o = t&127, quarter q = t>>7), j-quarter per thread ----
    const int o = t & 127;
    const int q = t >> 7;
    float acc0 = 0.f, acc1 = 0.f, acc2 = 0.f, acc3 = 0.f;
    const int jb = q * 128;
    for (int j = jb; j < jb + 128; j += 4) {
        const float4 p0 = ((const float4*)&e_l[0 * NN])[j >> 2];
        const float4 p1 = ((const float4*)&e_l[1 * NN])[j >> 2];
        const float4 p2 = ((const float4*)&e_l[2 * NN])[j >> 2];
        const float4 p3 = ((const float4*)&e_l[3 * NN])[j >> 2];
        float wv;
        wv = whB[(size_t)(j + 0) * FOUT + o];
        acc0 = fmaf(p0.x, wv, acc0); acc1 = fmaf(p1.x, wv, acc1);
        acc2 = fmaf(p2.x, wv, acc2); acc3 = fmaf(p3.x, wv, acc3);
        wv = whB[(size_t)(j + 1) * FOUT + o];
        acc0 = fmaf(p0.y, wv, acc0); acc1 = fmaf(p1.y, wv, acc1);
        acc2 = fmaf(p2.y, wv, acc2); acc3 = fmaf(p3.y, wv, acc3);
        wv = whB[(size_t)(j + 2) * FOUT + o];
        acc0 = fmaf(p0.z, wv, acc0); acc1 = fmaf(p1.z, wv, acc1);
        acc2 = fmaf(p2.z, wv, acc2); acc3 = fmaf(p3.z, wv, acc3);
        wv = whB[(size_t)(j + 3) * FOUT + o];
        acc0 = fmaf(p0.w, wv, acc0); acc1 = fmaf(p1.w, wv, acc1);
        acc2 = fmaf(p2.w, wv, acc2); acc3 = fmaf(p3.w, wv, acc3);
    }

    if (q) {
        parts[((q - 1) * 4 + 0) * 128 + o] = acc0;
        parts[((q - 1) * 4 + 1) * 128 + o] = acc1;
        parts[((q - 1) * 4 + 2) * 128 + o] = acc2;
        parts[((q - 1) * 4 + 3) * 128 + o] = acc3;
    }
    __syncthreads();                                   // S6
    if (q == 0) {
        const float rs0 = 1.0f / (scal[0] + scal[1]);
        const float rs1 = 1.0f / (scal[2] + scal[3]);
        const float rs2 = 1.0f / (scal[4] + scal[5]);
        const float rs3 = 1.0f / (scal[6] + scal[7]);
        float h0 = (acc0 + parts[(0 * 4 + 0) * 128 + o]) +
                   (parts[(1 * 4 + 0) * 128 + o] + parts[(2 * 4 + 0) * 128 + o]);
        float h1 = (acc1 + parts[(0 * 4 + 1) * 128 + o]) +
                   (parts[(1 * 4 + 1) * 128 + o] + parts[(2 * 4 + 1) * 128 + o]);
        float h2 = (acc2 + parts[(0 * 4 + 2) * 128 + o]) +
                   (parts[(1 * 4 + 2) * 128 + o] + parts[(2 * 4 + 2) * 128 + o]);
        float h3 = (acc3 + parts[(0 * 4 + 3) * 128 + o]) +
                   (parts[(1 * 4 + 3) * 128 + o] + parts[(2 * 4 + 3) * 128 + o]);
        h0 *= rs0; h1 *= rs1; h2 *= rs2; h3 *= rs3;
        float* orow = out + (size_t)(b * NN + i0) * FOUT + o;
        orow[0 * FOUT] = (h0 > 0.f) ? h0 : expm1f(h0);
        orow[1 * FOUT] = (h1 > 0.f) ? h1 : expm1f(h1);
        orow[2 * FOUT] = (h2 > 0.f) ? h2 : expm1f(h2);
        orow[3 * FOUT] = (h3 > 0.f) ? h3 : expm1f(h3);
    }
}

// ---------------------------------------------------------------------------
extern "C" void kernel_launch(void* const* d_in, const int* in_sizes, int n_in,
                              void* d_out, int out_size, void* d_ws, size_t ws_size,
                              hipStream_t stream) {
    const float* x    = (const float*)d_in[0];
    const int*   adj  = (const int*)d_in[1];
    const float* W    = (const float*)d_in[2];
    const float* a_fc = (const float*)d_in[3];
    float* out = (float*)d_out;

    float* ws       = (float*)d_ws;
    float* Wh       = ws;                    // 131072 floats
    float* u        = ws + 131072;           // 1024
    float* partials = ws + 131072 + 1024;    // 256
    int*   ctr      = (int*)(ws + 131072 + 1024 + 256);

    wh_u_kernel<<<dim3(256), dim3(512), 0, stream>>>(x, W, a_fc, Wh, u, ctr);
    gat_main_kernel<<<dim3(NBLK2), dim3(512), 0, stream>>>(Wh, u, a_fc, adj,
                                                           out, partials, ctr);
}

// Round 7
// 29.089 us; speedup vs baseline: 1.4797x; 1.4797x over previous
//
#include <hip/hip_runtime.h>
#include <math.h>

constexpr int BB   = 2;
constexpr int NN   = 512;
constexpr int FIN  = 256;
constexpr int FOUT = 128;

// ---------------------------------------------------------------------------
// Kernel A: Wh = x@W and u_i = sum_o a_o*Wh[i,o]   (unchanged from R4 base)
// 256 blocks x 512 thr, 4 rows/block.
// ---------------------------------------------------------------------------
__global__ __launch_bounds__(512) void wh_u_kernel(const float* __restrict__ x,
                                                   const float* __restrict__ W,
                                                   const float* __restrict__ a_fc,
                                                   float* __restrict__ Wh,
                                                   float* __restrict__ u) {
    __shared__ float  xs[4][FIN];
    __shared__ float4 part[4][4][32];
    __shared__ float  upart[8][4];

    const int t  = threadIdx.x;
    const int g0 = blockIdx.x * 4;

    if (t < 256)
        ((float4*)xs)[t] = ((const float4*)(x + (size_t)g0 * FIN))[t];
    __syncthreads();

    const int rl = t >> 7;
    const int fs = (t >> 5) & 3;
    const int og = t & 31;
    const float* xr = &xs[rl][fs * 64];
    const float4* W4 = (const float4*)W;

    float4 acc = {0.f, 0.f, 0.f, 0.f};
#pragma unroll 8
    for (int f = 0; f < 64; ++f) {
        const float  xv = xr[f];
        const float4 wv = W4[(size_t)(fs * 64 + f) * 32 + og];
        acc.x = fmaf(xv, wv.x, acc.x);
        acc.y = fmaf(xv, wv.y, acc.y);
        acc.z = fmaf(xv, wv.z, acc.z);
        acc.w = fmaf(xv, wv.w, acc.w);
    }
    part[rl][fs][og] = acc;
    __syncthreads();

    if (t < 128) {
        const int crl = t & 3;
        const int cog = t >> 2;
        const float4 s0 = part[crl][0][cog];
        const float4 s1 = part[crl][1][cog];
        const float4 s2 = part[crl][2][cog];
        const float4 s3 = part[crl][3][cog];
        float4 w4;
        w4.x = (s0.x + s1.x) + (s2.x + s3.x);
        w4.y = (s0.y + s1.y) + (s2.y + s3.y);
        w4.z = (s0.z + s1.z) + (s2.z + s3.z);
        w4.w = (s0.w + s1.w) + (s2.w + s3.w);
        ((float4*)(Wh + (size_t)(g0 + crl) * FOUT))[cog] = w4;

        const float4 a4 = ((const float4*)a_fc)[cog];
        float pa = w4.x * a4.x + w4.y * a4.y + w4.z * a4.z + w4.w * a4.w;
#pragma unroll
        for (int off = 32; off >= 4; off >>= 1) pa += __shfl_down(pa, off);
        if ((t & 63) < 4) upart[t >> 6][t & 3] = pa;
    }
    __syncthreads();
    if (t < 4) {
        u[g0 + t] = upart[0][t] + upart[1][t];
    }
}

// ---------------------------------------------------------------------------
// Kernel B: e + sumsq partials   (unchanged from R4 base)
// grid (32,8,2) x 256 thr; tile 64i x 16j; o-chunk per wave, i-slice in regs,
// j-rows via LDS broadcast.
// ---------------------------------------------------------------------------
__global__ __launch_bounds__(256) void e_kernel(const float* __restrict__ Wh,
                                                const float* __restrict__ u,
                                                const float* __restrict__ a_fc,
                                                float* __restrict__ e_buf,
                                                float* __restrict__ partials) {
    __shared__ float whi[64][132];
    __shared__ float whj[16][132];
    __shared__ float a2[FOUT];
    __shared__ float usi[64];
    __shared__ float usj[16];
    __shared__ float parts[16][4][65];
    __shared__ float red[4];

    const int t   = threadIdx.x;
    const int bj0 = blockIdx.x * 16;
    const int bi0 = blockIdx.y * 64;
    const int b   = blockIdx.z;
    const float* whb = Wh + (size_t)(b * NN) * FOUT;

#pragma unroll
    for (int it = 0; it < 8; ++it) {
        const int idx = it * 256 + t;
        const int row = idx >> 5, c4 = idx & 31;
        *(float4*)&whi[row][c4 * 4] =
            *(const float4*)(whb + (size_t)(bi0 + row) * FOUT + c4 * 4);
    }
#pragma unroll
    for (int it = 0; it < 2; ++it) {
        const int idx = it * 256 + t;
        const int row = idx >> 5, c4 = idx & 31;
        *(float4*)&whj[row][c4 * 4] =
            *(const float4*)(whb + (size_t)(bj0 + row) * FOUT + c4 * 4);
    }
    if (t < 64)                usi[t]       = u[b * NN + bi0 + t];
    else if (t < 80)           usj[t - 64]  = u[b * NN + bj0 + (t - 64)];
    else if (t >= 128)         a2[t - 128]  = 0.4f * a_fc[t - 128];
    __syncthreads();

    const int w    = t >> 6;
    const int lane = t & 63;
    const int ob   = w * 32;

    float4 iv[8], av[8];
#pragma unroll
    for (int k = 0; k < 8; ++k) {
        iv[k] = *(const float4*)&whi[lane][ob + 4 * k];
        av[k] = *(const float4*)&a2[ob + 4 * k];
    }

#pragma unroll 2
    for (int j = 0; j < 16; ++j) {
        float4 acc = {0.f, 0.f, 0.f, 0.f};
#pragma unroll
        for (int k = 0; k < 8; ++k) {
            const float4 jv = *(const float4*)&whj[j][ob + 4 * k];
            float s;
            s = iv[k].x + jv.x; acc.x = fmaf(av[k].x, fabsf(s), acc.x);
            s = iv[k].y + jv.y; acc.y = fmaf(av[k].y, fabsf(s), acc.y);
            s = iv[k].z + jv.z; acc.z = fmaf(av[k].z, fabsf(s), acc.z);
            s = iv[k].w + jv.w; acc.w = fmaf(av[k].w, fabsf(s), acc.w);
        }
        parts[j][w][lane] = (acc.x + acc.y) + (acc.z + acc.w);
    }
    __syncthreads();

    const int i  = t >> 2;
    const int jq = t & 3;
    const float ui = usi[i];
    float ev[4];
    float ss = 0.f;
#pragma unroll
    for (int jj = 0; jj < 4; ++jj) {
        const int j = jq * 4 + jj;
        const float s4 = (parts[j][0][i] + parts[j][1][i]) +
                         (parts[j][2][i] + parts[j][3][i]);
        const float v = fmaf(0.6f, ui + usj[j], s4);
        ss = fmaf(v, v, ss);
        ev[jj] = v;
    }
    float4 e4 = {ev[0], ev[1], ev[2], ev[3]};
    *(float4*)&e_buf[(size_t)(b * NN + bi0 + i) * NN + bj0 + jq * 4] = e4;

#pragma unroll
    for (int off = 32; off; off >>= 1) ss += __shfl_down(ss, off);
    if ((t & 63) == 0) red[t >> 6] = ss;
    __syncthreads();
    if (t == 0)
        partials[(blockIdx.z * 8 + blockIdx.y) * 32 + blockIdx.x] =
            (red[0] + red[1]) + (red[2] + red[3]);
}

// ---------------------------------------------------------------------------
// Kernel C: norm -> mask -> softmax -> att@Wh -> elu
// NEW: 8 rows/block (was 4). 256 blocks x 512 thr: (8 rows) x (64-o half).
// Wave w owns row w's softmax (pure shfl_xor). PV: j-eighth per wave,
// combine via LDS. Halves Wh L2 traffic (64MB -> 32MB) and block count.
// ---------------------------------------------------------------------------
__global__ __launch_bounds__(512) void softmax_pv_kernel(
        const float* __restrict__ e_buf, const int* __restrict__ adj,
        const float* __restrict__ Wh, const float* __restrict__ partials,
        float* __restrict__ out) {
    __shared__ float p[8][NN];          // 16 KB
    __shared__ float hb[7][8][64];      // 14 KB  (PV partials, waves 1..7)
    __shared__ float red[8];
    __shared__ float rsv[8];

    const int t    = threadIdx.x;
    const int w    = t >> 6;            // 0..7
    const int lane = t & 63;

    // global Frobenius norm from 512 partials (one per thread)
    float v = partials[t];
#pragma unroll
    for (int off = 32; off; off >>= 1) v += __shfl_down(v, off);
    if (lane == 0) red[w] = v;
    __syncthreads();
    const float inv_norm = 1.0f / sqrtf(((red[0] + red[1]) + (red[2] + red[3])) +
                                        ((red[4] + red[5]) + (red[6] + red[7])));

    const int g0  = (blockIdx.x & 127) * 8;   // row group (8 rows, same batch)
    const int row = g0 + w;

    // --- softmax: wave w owns row w entirely (512 = 64 lanes x 8) ---
    const float4* er4 = (const float4*)(e_buf + (size_t)row * NN);
    const int4*   ad4 = (const int4*)(adj + (size_t)row * NN);
    const float4 ea = er4[lane],     eb = er4[lane + 64];
    const int4   aa = ad4[lane],     ab = ad4[lane + 64];

    float va[8];
    va[0] = aa.x ? ea.x * inv_norm : -INFINITY;
    va[1] = aa.y ? ea.y * inv_norm : -INFINITY;
    va[2] = aa.z ? ea.z * inv_norm : -INFINITY;
    va[3] = aa.w ? ea.w * inv_norm : -INFINITY;
    va[4] = ab.x ? eb.x * inv_norm : -INFINITY;
    va[5] = ab.y ? eb.y * inv_norm : -INFINITY;
    va[6] = ab.z ? eb.z * inv_norm : -INFINITY;
    va[7] = ab.w ? eb.w * inv_norm : -INFINITY;

    float mx = va[0];
#pragma unroll
    for (int c = 1; c < 8; ++c) mx = fmaxf(mx, va[c]);
#pragma unroll
    for (int off = 32; off; off >>= 1) mx = fmaxf(mx, __shfl_xor(mx, off));

    float pv[8], sum = 0.f;
#pragma unroll
    for (int c = 0; c < 8; ++c) { pv[c] = expf(va[c] - mx); sum += pv[c]; }
    float4 pa = {pv[0], pv[1], pv[2], pv[3]};
    float4 pb = {pv[4], pv[5], pv[6], pv[7]};
    ((float4*)&p[w][0])[lane]      = pa;
    ((float4*)&p[w][0])[lane + 64] = pb;

#pragma unroll
    for (int off = 32; off; off >>= 1) sum += __shfl_xor(sum, off);
    if (lane == 0) rsv[w] = 1.0f / sum;
    __syncthreads();

    // --- PV: o = 64-half x lane, wave w handles j in [64w, 64w+64) ---
    const int oo = lane;
    const int o  = (blockIdx.x >> 7) * 64 + oo;
    const int b  = g0 >> 9;
    const float* whb = Wh + (size_t)(b * NN) * FOUT;
    const int j0 = w * 64;

    float acc[8] = {0.f,0.f,0.f,0.f,0.f,0.f,0.f,0.f};
    for (int j = j0; j < j0 + 64; j += 4) {
        float4 pr[8];
#pragma unroll
        for (int r = 0; r < 8; ++r) pr[r] = *(const float4*)&p[r][j];
#define PV_STEP(Q, SEL)                                                \
        {                                                              \
            const float wv = whb[(size_t)(j + Q) * FOUT + o];          \
            acc[0] = fmaf(pr[0].SEL, wv, acc[0]);                      \
            acc[1] = fmaf(pr[1].SEL, wv, acc[1]);                      \
            acc[2] = fmaf(pr[2].SEL, wv, acc[2]);                      \
            acc[3] = fmaf(pr[3].SEL, wv, acc[3]);                      \
            acc[4] = fmaf(pr[4].SEL, wv, acc[4]);                      \
            acc[5] = fmaf(pr[5].SEL, wv, acc[5]);                      \
            acc[6] = fmaf(pr[6].SEL, wv, acc[6]);                      \
            acc[7] = fmaf(pr[7].SEL, wv, acc[7]);                      \
        }
        PV_STEP(0, x)
        PV_STEP(1, y)
        PV_STEP(2, z)
        PV_STEP(3, w)
#undef PV_STEP
    }

    if (w) {
#pragma unroll
        for (int r = 0; r < 8; ++r) hb[w - 1][r][oo] = acc[r];
    }
    __syncthreads();
    if (w == 0) {
#pragma unroll
        for (int r = 0; r < 8; ++r) {
            float h = acc[r];
#pragma unroll
            for (int k = 0; k < 7; ++k) h += hb[k][r][oo];
            h *= rsv[r];
            out[(size_t)(g0 + r) * FOUT + o] = (h > 0.f) ? h : expm1f(h);
        }
    }
}

// ---------------------------------------------------------------------------
extern "C" void kernel_launch(void* const* d_in, const int* in_sizes, int n_in,
                              void* d_out, int out_size, void* d_ws, size_t ws_size,
                              hipStream_t stream) {
    const float* x    = (const float*)d_in[0];
    const int*   adj  = (const int*)d_in[1];
    const float* W    = (const float*)d_in[2];
    const float* a_fc = (const float*)d_in[3];
    float* out = (float*)d_out;

    float* ws       = (float*)d_ws;
    float* Wh       = ws;                        // 131072 floats
    float* u        = ws + 131072;               // 1024
    float* partials = ws + 131072 + 1024;        // 512
    float* e_buf    = ws + 131072 + 1024 + 512;  // 524288

    wh_u_kernel<<<dim3(BB * NN / 4), dim3(512), 0, stream>>>(x, W, a_fc, Wh, u);
    e_kernel<<<dim3(NN / 16, NN / 64, BB), dim3(256), 0, stream>>>(Wh, u, a_fc, e_buf, partials);
    softmax_pv_kernel<<<dim3(256), dim3(512), 0, stream>>>(e_buf, adj, Wh, partials, out);
}

// Round 8
// 25.782 us; speedup vs baseline: 1.6694x; 1.1283x over previous
//
#include <hip/hip_runtime.h>
#include <math.h>

constexpr int BB   = 2;
constexpr int NN   = 512;
constexpr int FIN  = 256;
constexpr int FOUT = 128;

// ---------------------------------------------------------------------------
// Kernel A: Wh = x@W and u_i = sum_o a_o*Wh[i,o]   (R4 proven version)
// 256 blocks x 512 thr, 4 rows/block.
// ---------------------------------------------------------------------------
__global__ __launch_bounds__(512) void wh_u_kernel(const float* __restrict__ x,
                                                   const float* __restrict__ W,
                                                   const float* __restrict__ a_fc,
                                                   float* __restrict__ Wh,
                                                   float* __restrict__ u) {
    __shared__ float  xs[4][FIN];
    __shared__ float4 part[4][4][32];
    __shared__ float  upart[8][4];

    const int t  = threadIdx.x;
    const int g0 = blockIdx.x * 4;

    if (t < 256)
        ((float4*)xs)[t] = ((const float4*)(x + (size_t)g0 * FIN))[t];
    __syncthreads();

    const int rl = t >> 7;
    const int fs = (t >> 5) & 3;
    const int og = t & 31;
    const float* xr = &xs[rl][fs * 64];
    const float4* W4 = (const float4*)W;

    float4 acc = {0.f, 0.f, 0.f, 0.f};
#pragma unroll 8
    for (int f = 0; f < 64; ++f) {
        const float  xv = xr[f];
        const float4 wv = W4[(size_t)(fs * 64 + f) * 32 + og];
        acc.x = fmaf(xv, wv.x, acc.x);
        acc.y = fmaf(xv, wv.y, acc.y);
        acc.z = fmaf(xv, wv.z, acc.z);
        acc.w = fmaf(xv, wv.w, acc.w);
    }
    part[rl][fs][og] = acc;
    __syncthreads();

    if (t < 128) {
        const int crl = t & 3;
        const int cog = t >> 2;
        const float4 s0 = part[crl][0][cog];
        const float4 s1 = part[crl][1][cog];
        const float4 s2 = part[crl][2][cog];
        const float4 s3 = part[crl][3][cog];
        float4 w4;
        w4.x = (s0.x + s1.x) + (s2.x + s3.x);
        w4.y = (s0.y + s1.y) + (s2.y + s3.y);
        w4.z = (s0.z + s1.z) + (s2.z + s3.z);
        w4.w = (s0.w + s1.w) + (s2.w + s3.w);
        ((float4*)(Wh + (size_t)(g0 + crl) * FOUT))[cog] = w4;

        const float4 a4 = ((const float4*)a_fc)[cog];
        float pa = w4.x * a4.x + w4.y * a4.y + w4.z * a4.z + w4.w * a4.w;
#pragma unroll
        for (int off = 32; off >= 4; off >>= 1) pa += __shfl_down(pa, off);
        if ((t & 63) < 4) upart[t >> 6][t & 3] = pa;
    }
    __syncthreads();
    if (t < 4) {
        u[g0 + t] = upart[0][t] + upart[1][t];
    }
}

// ---------------------------------------------------------------------------
// Kernel B: e + sumsq partials.
// NEW: tile 32i x 16j (was 64x16) -> grid (32,16,2) = 1024 blocks x 256 thr.
// LDS ~35KB, ~70 VGPR -> 4 blocks/CU = 16 waves/CU = 4 waves/SIMD (2x TLP).
// Wave w owns o-chunk [32w,32w+32); lane: i = lane&31 (reg i-slice),
// jh = lane>>5 picks j-half; j-rows via LDS broadcast (2-way alias = free).
// ---------------------------------------------------------------------------
__global__ __launch_bounds__(256) void e_kernel(const float* __restrict__ Wh,
                                                const float* __restrict__ u,
                                                const float* __restrict__ a_fc,
                                                float* __restrict__ e_buf,
                                                float* __restrict__ partials) {
    __shared__ float whi[32][132];
    __shared__ float whj[16][132];
    __shared__ float a2[FOUT];
    __shared__ float usi[32];
    __shared__ float usj[16];
    __shared__ float parts[16][4][33];
    __shared__ float red[4];

    const int t   = threadIdx.x;
    const int bj0 = blockIdx.x * 16;
    const int bi0 = blockIdx.y * 32;
    const int b   = blockIdx.z;
    const float* whb = Wh + (size_t)(b * NN) * FOUT;

#pragma unroll
    for (int it = 0; it < 4; ++it) {
        const int idx = it * 256 + t;
        const int row = idx >> 5, c4 = idx & 31;
        *(float4*)&whi[row][c4 * 4] =
            *(const float4*)(whb + (size_t)(bi0 + row) * FOUT + c4 * 4);
    }
#pragma unroll
    for (int it = 0; it < 2; ++it) {
        const int idx = it * 256 + t;
        const int row = idx >> 5, c4 = idx & 31;
        *(float4*)&whj[row][c4 * 4] =
            *(const float4*)(whb + (size_t)(bj0 + row) * FOUT + c4 * 4);
    }
    if (t < 32)            usi[t]       = u[b * NN + bi0 + t];
    else if (t < 48)       usj[t - 32]  = u[b * NN + bj0 + (t - 32)];
    else if (t >= 128)     a2[t - 128]  = 0.4f * a_fc[t - 128];
    __syncthreads();

    const int w    = t >> 6;       // o-chunk 0..3
    const int lane = t & 63;
    const int i    = lane & 31;    // i-row in tile
    const int jh   = lane >> 5;    // j-half: j in [8*jh, 8*jh+8)
    const int ob   = w * 32;

    float4 iv[8], av[8];
#pragma unroll
    for (int k = 0; k < 8; ++k) {
        iv[k] = *(const float4*)&whi[i][ob + 4 * k];
        av[k] = *(const float4*)&a2[ob + 4 * k];
    }

#pragma unroll
    for (int jj = 0; jj < 8; ++jj) {
        const int j = jh * 8 + jj;
        float4 acc = {0.f, 0.f, 0.f, 0.f};
#pragma unroll
        for (int k = 0; k < 8; ++k) {
            const float4 jv = *(const float4*)&whj[j][ob + 4 * k];
            float s;
            s = iv[k].x + jv.x; acc.x = fmaf(av[k].x, fabsf(s), acc.x);
            s = iv[k].y + jv.y; acc.y = fmaf(av[k].y, fabsf(s), acc.y);
            s = iv[k].z + jv.z; acc.z = fmaf(av[k].z, fabsf(s), acc.z);
            s = iv[k].w + jv.w; acc.w = fmaf(av[k].w, fabsf(s), acc.w);
        }
        parts[j][w][i] = (acc.x + acc.y) + (acc.z + acc.w);
    }
    __syncthreads();

    // combine: thread -> i = t>>3 (0..31), j-pair jp = (t&7)*2
    const int ci = t >> 3;
    const int jp = (t & 7) * 2;
    const float ui = usi[ci];

    const float S0 = (parts[jp][0][ci] + parts[jp][1][ci]) +
                     (parts[jp][2][ci] + parts[jp][3][ci]);
    const float v0 = fmaf(0.6f, ui + usj[jp], S0);
    const float S1 = (parts[jp + 1][0][ci] + parts[jp + 1][1][ci]) +
                     (parts[jp + 1][2][ci] + parts[jp + 1][3][ci]);
    const float v1 = fmaf(0.6f, ui + usj[jp + 1], S1);
    float ss = fmaf(v0, v0, v1 * v1);

    float2 e2 = {v0, v1};
    *(float2*)&e_buf[(size_t)(b * NN + bi0 + ci) * NN + bj0 + jp] = e2;

#pragma unroll
    for (int off = 32; off; off >>= 1) ss += __shfl_down(ss, off);
    if ((t & 63) == 0) red[t >> 6] = ss;
    __syncthreads();
    if (t == 0)
        partials[(blockIdx.z * 16 + blockIdx.y) * 32 + blockIdx.x] =
            (red[0] + red[1]) + (red[2] + red[3]);
}

// ---------------------------------------------------------------------------
// Kernel C: norm -> mask -> softmax -> att@Wh -> elu  (R4 proven version;
// only the partials reduce widened to 1024 entries)
// 512 blocks x 256 thr: (4 rows) x (64-o half). Wave w owns row w.
// ---------------------------------------------------------------------------
__global__ __launch_bounds__(256) void softmax_pv_kernel(
        const float* __restrict__ e_buf, const int* __restrict__ adj,
        const float* __restrict__ Wh, const float* __restrict__ partials,
        float* __restrict__ out) {
    __shared__ float p[4][NN];
    __shared__ float hb[3][4][64];
    __shared__ float red[4];
    __shared__ float rsv[4];

    const int t    = threadIdx.x;
    const int w    = t >> 6;
    const int lane = t & 63;

    // global Frobenius norm from 1024 partials
    float v = (partials[t] + partials[t + 256]) +
              (partials[t + 512] + partials[t + 768]);
#pragma unroll
    for (int off = 32; off; off >>= 1) v += __shfl_down(v, off);
    if (lane == 0) red[w] = v;
    __syncthreads();
    const float inv_norm = 1.0f / sqrtf((red[0] + red[1]) + (red[2] + red[3]));

    const int g0  = (blockIdx.x & 255) * 4;
    const int row = g0 + w;

    const float4* er4 = (const float4*)(e_buf + (size_t)row * NN);
    const int4*   ad4 = (const int4*)(adj + (size_t)row * NN);
    const float4 ea = er4[lane],     eb = er4[lane + 64];
    const int4   aa = ad4[lane],     ab = ad4[lane + 64];

    float va[8];
    va[0] = aa.x ? ea.x * inv_norm : -INFINITY;
    va[1] = aa.y ? ea.y * inv_norm : -INFINITY;
    va[2] = aa.z ? ea.z * inv_norm : -INFINITY;
    va[3] = aa.w ? ea.w * inv_norm : -INFINITY;
    va[4] = ab.x ? eb.x * inv_norm : -INFINITY;
    va[5] = ab.y ? eb.y * inv_norm : -INFINITY;
    va[6] = ab.z ? eb.z * inv_norm : -INFINITY;
    va[7] = ab.w ? eb.w * inv_norm : -INFINITY;

    float mx = va[0];
#pragma unroll
    for (int c = 1; c < 8; ++c) mx = fmaxf(mx, va[c]);
#pragma unroll
    for (int off = 32; off; off >>= 1) mx = fmaxf(mx, __shfl_xor(mx, off));

    float pv[8], sum = 0.f;
#pragma unroll
    for (int c = 0; c < 8; ++c) { pv[c] = expf(va[c] - mx); sum += pv[c]; }
    float4 pa = {pv[0], pv[1], pv[2], pv[3]};
    float4 pb = {pv[4], pv[5], pv[6], pv[7]};
    ((float4*)&p[w][0])[lane]      = pa;
    ((float4*)&p[w][0])[lane + 64] = pb;

#pragma unroll
    for (int off = 32; off; off >>= 1) sum += __shfl_xor(sum, off);
    if (lane == 0) rsv[w] = 1.0f / sum;
    __syncthreads();

    const int oo = lane;
    const int o  = (blockIdx.x >> 8) * 64 + oo;
    const int b  = g0 >> 9;
    const float* whb = Wh + (size_t)(b * NN) * FOUT;
    const int j0 = w * 128;

    float acc[4] = {0.f, 0.f, 0.f, 0.f};
    for (int j = j0; j < j0 + 128; j += 4) {
        const float4 p0 = *(const float4*)&p[0][j];
        const float4 p1 = *(const float4*)&p[1][j];
        const float4 p2 = *(const float4*)&p[2][j];
        const float4 p3 = *(const float4*)&p[3][j];
        const float q0[4] = {p0.x, p0.y, p0.z, p0.w};
        const float q1[4] = {p1.x, p1.y, p1.z, p1.w};
        const float q2[4] = {p2.x, p2.y, p2.z, p2.w};
        const float q3[4] = {p3.x, p3.y, p3.z, p3.w};
#pragma unroll
        for (int q = 0; q < 4; ++q) {
            const float wv = whb[(size_t)(j + q) * FOUT + o];
            acc[0] = fmaf(q0[q], wv, acc[0]);
            acc[1] = fmaf(q1[q], wv, acc[1]);
            acc[2] = fmaf(q2[q], wv, acc[2]);
            acc[3] = fmaf(q3[q], wv, acc[3]);
        }
    }

    if (w) {
        hb[w - 1][0][oo] = acc[0];
        hb[w - 1][1][oo] = acc[1];
        hb[w - 1][2][oo] = acc[2];
        hb[w - 1][3][oo] = acc[3];
    }
    __syncthreads();
    if (w == 0) {
#pragma unroll
        for (int r = 0; r < 4; ++r) {
            const float hv = (acc[r] + hb[0][r][oo] + hb[1][r][oo] + hb[2][r][oo]) * rsv[r];
            out[(size_t)(g0 + r) * FOUT + o] = (hv > 0.f) ? hv : expm1f(hv);
        }
    }
}

// ---------------------------------------------------------------------------
extern "C" void kernel_launch(void* const* d_in, const int* in_sizes, int n_in,
                              void* d_out, int out_size, void* d_ws, size_t ws_size,
                              hipStream_t stream) {
    const float* x    = (const float*)d_in[0];
    const int*   adj  = (const int*)d_in[1];
    const float* W    = (const float*)d_in[2];
    const float* a_fc = (const float*)d_in[3];
    float* out = (float*)d_out;

    float* ws       = (float*)d_ws;
    float* Wh       = ws;                         // 131072 floats
    float* u        = ws + 131072;                // 1024
    float* partials = ws + 131072 + 1024;         // 1024
    float* e_buf    = ws + 131072 + 2048;         // 524288

    wh_u_kernel<<<dim3(BB * NN / 4), dim3(512), 0, stream>>>(x, W, a_fc, Wh, u);
    e_kernel<<<dim3(NN / 16, NN / 32, BB), dim3(256), 0, stream>>>(Wh, u, a_fc, e_buf, partials);
    softmax_pv_kernel<<<dim3(512), dim3(256), 0, stream>>>(e_buf, adj, Wh, partials, out);
}

// Round 9
// 25.256 us; speedup vs baseline: 1.7042x; 1.0208x over previous
//
#include <hip/hip_runtime.h>
#include <math.h>

constexpr int BB   = 2;
constexpr int NN   = 512;
constexpr int FIN  = 256;
constexpr int FOUT = 128;

// ---------------------------------------------------------------------------
// Kernel A: Wh = x@W and u_i = sum_o a_o*Wh[i,o]
// NEW: 512 blocks x 256 thr, 2 rows/block, register-blocked over rows:
// each W float4 is loaded once and applied to both rows (2 fma/load, 2
// independent acc chains). W L2 traffic halves to 64MB; 2 blocks/CU.
// ---------------------------------------------------------------------------
__global__ __launch_bounds__(256) void wh_u_kernel(const float* __restrict__ x,
                                                   const float* __restrict__ W,
                                                   const float* __restrict__ a_fc,
                                                   float* __restrict__ Wh,
                                                   float* __restrict__ u) {
    __shared__ float  xs[2][FIN];
    __shared__ float4 part[2][8][32];

    const int t  = threadIdx.x;
    const int g0 = blockIdx.x * 2;

    if (t < 128)
        ((float4*)xs)[t] = ((const float4*)(x + (size_t)g0 * FIN))[t];
    __syncthreads();

    const int fs = t >> 5;    // 0..7  f-slice (32 f's)
    const int og = t & 31;    // o-quad
    const float* x0 = &xs[0][fs * 32];
    const float* x1 = &xs[1][fs * 32];
    const float4* W4 = (const float4*)W;

    float4 a0 = {0.f, 0.f, 0.f, 0.f};
    float4 a1 = {0.f, 0.f, 0.f, 0.f};
#pragma unroll 8
    for (int f = 0; f < 32; ++f) {
        const float4 wv = W4[(size_t)(fs * 32 + f) * 32 + og];
        const float v0 = x0[f];
        const float v1 = x1[f];
        a0.x = fmaf(v0, wv.x, a0.x); a1.x = fmaf(v1, wv.x, a1.x);
        a0.y = fmaf(v0, wv.y, a0.y); a1.y = fmaf(v1, wv.y, a1.y);
        a0.z = fmaf(v0, wv.z, a0.z); a1.z = fmaf(v1, wv.z, a1.z);
        a0.w = fmaf(v0, wv.w, a0.w); a1.w = fmaf(v1, wv.w, a1.w);
    }
    part[0][fs][og] = a0;
    part[1][fs][og] = a1;
    __syncthreads();

    if (t < 64) {
        const int rl = t >> 5;   // 0..1
        const int o4 = t & 31;
        float4 s0 = part[rl][0][o4], s1 = part[rl][1][o4];
        float4 s2 = part[rl][2][o4], s3 = part[rl][3][o4];
        float4 s4 = part[rl][4][o4], s5 = part[rl][5][o4];
        float4 s6 = part[rl][6][o4], s7 = part[rl][7][o4];
        float4 w4;
        w4.x = ((s0.x + s1.x) + (s2.x + s3.x)) + ((s4.x + s5.x) + (s6.x + s7.x));
        w4.y = ((s0.y + s1.y) + (s2.y + s3.y)) + ((s4.y + s5.y) + (s6.y + s7.y));
        w4.z = ((s0.z + s1.z) + (s2.z + s3.z)) + ((s4.z + s5.z) + (s6.z + s7.z));
        w4.w = ((s0.w + s1.w) + (s2.w + s3.w)) + ((s4.w + s5.w) + (s6.w + s7.w));
        ((float4*)(Wh + (size_t)(g0 + rl) * FOUT))[o4] = w4;

        const float4 a4 = ((const float4*)a_fc)[o4];
        float pa = w4.x * a4.x + w4.y * a4.y + w4.z * a4.z + w4.w * a4.w;
#pragma unroll
        for (int off = 16; off; off >>= 1) pa += __shfl_down(pa, off, 32);
        if (o4 == 0) u[g0 + rl] = pa;
    }
}

// ---------------------------------------------------------------------------
// Kernel B: e + sumsq partials.  (FROZEN from R8 — proven 4-blocks/CU winner)
// tile 32i x 16j, grid (32,16,2) = 1024 blocks x 256 thr.
// ---------------------------------------------------------------------------
__global__ __launch_bounds__(256) void e_kernel(const float* __restrict__ Wh,
                                                const float* __restrict__ u,
                                                const float* __restrict__ a_fc,
                                                float* __restrict__ e_buf,
                                                float* __restrict__ partials) {
    __shared__ float whi[32][132];
    __shared__ float whj[16][132];
    __shared__ float a2[FOUT];
    __shared__ float usi[32];
    __shared__ float usj[16];
    __shared__ float parts[16][4][33];
    __shared__ float red[4];

    const int t   = threadIdx.x;
    const int bj0 = blockIdx.x * 16;
    const int bi0 = blockIdx.y * 32;
    const int b   = blockIdx.z;
    const float* whb = Wh + (size_t)(b * NN) * FOUT;

#pragma unroll
    for (int it = 0; it < 4; ++it) {
        const int idx = it * 256 + t;
        const int row = idx >> 5, c4 = idx & 31;
        *(float4*)&whi[row][c4 * 4] =
            *(const float4*)(whb + (size_t)(bi0 + row) * FOUT + c4 * 4);
    }
#pragma unroll
    for (int it = 0; it < 2; ++it) {
        const int idx = it * 256 + t;
        const int row = idx >> 5, c4 = idx & 31;
        *(float4*)&whj[row][c4 * 4] =
            *(const float4*)(whb + (size_t)(bj0 + row) * FOUT + c4 * 4);
    }
    if (t < 32)            usi[t]       = u[b * NN + bi0 + t];
    else if (t < 48)       usj[t - 32]  = u[b * NN + bj0 + (t - 32)];
    else if (t >= 128)     a2[t - 128]  = 0.4f * a_fc[t - 128];
    __syncthreads();

    const int w    = t >> 6;
    const int lane = t & 63;
    const int i    = lane & 31;
    const int jh   = lane >> 5;
    const int ob   = w * 32;

    float4 iv[8], av[8];
#pragma unroll
    for (int k = 0; k < 8; ++k) {
        iv[k] = *(const float4*)&whi[i][ob + 4 * k];
        av[k] = *(const float4*)&a2[ob + 4 * k];
    }

#pragma unroll
    for (int jj = 0; jj < 8; ++jj) {
        const int j = jh * 8 + jj;
        float4 acc = {0.f, 0.f, 0.f, 0.f};
#pragma unroll
        for (int k = 0; k < 8; ++k) {
            const float4 jv = *(const float4*)&whj[j][ob + 4 * k];
            float s;
            s = iv[k].x + jv.x; acc.x = fmaf(av[k].x, fabsf(s), acc.x);
            s = iv[k].y + jv.y; acc.y = fmaf(av[k].y, fabsf(s), acc.y);
            s = iv[k].z + jv.z; acc.z = fmaf(av[k].z, fabsf(s), acc.z);
            s = iv[k].w + jv.w; acc.w = fmaf(av[k].w, fabsf(s), acc.w);
        }
        parts[j][w][i] = (acc.x + acc.y) + (acc.z + acc.w);
    }
    __syncthreads();

    const int ci = t >> 3;
    const int jp = (t & 7) * 2;
    const float ui = usi[ci];

    const float S0 = (parts[jp][0][ci] + parts[jp][1][ci]) +
                     (parts[jp][2][ci] + parts[jp][3][ci]);
    const float v0 = fmaf(0.6f, ui + usj[jp], S0);
    const float S1 = (parts[jp + 1][0][ci] + parts[jp + 1][1][ci]) +
                     (parts[jp + 1][2][ci] + parts[jp + 1][3][ci]);
    const float v1 = fmaf(0.6f, ui + usj[jp + 1], S1);
    float ss = fmaf(v0, v0, v1 * v1);

    float2 e2 = {v0, v1};
    *(float2*)&e_buf[(size_t)(b * NN + bi0 + ci) * NN + bj0 + jp] = e2;

#pragma unroll
    for (int off = 32; off; off >>= 1) ss += __shfl_down(ss, off);
    if ((t & 63) == 0) red[t >> 6] = ss;
    __syncthreads();
    if (t == 0)
        partials[(blockIdx.z * 16 + blockIdx.y) * 32 + blockIdx.x] =
            (red[0] + red[1]) + (red[2] + red[3]);
}

// ---------------------------------------------------------------------------
// Kernel C: norm -> mask -> softmax -> att@Wh -> elu
// NEW: 1024 blocks x 256 thr: (4 rows) x (32-o quarter) -> 4 blocks/CU =
// 4 waves/SIMD (2x TLP vs R4). Softmax duplicated per o-quarter (pure-shfl,
// cheap). PV: 8 j-chunks of 64 (wave-half each), combine via LDS.
// ---------------------------------------------------------------------------
__global__ __launch_bounds__(256) void softmax_pv_kernel(
        const float* __restrict__ e_buf, const int* __restrict__ adj,
        const float* __restrict__ Wh, const float* __restrict__ partials,
        float* __restrict__ out) {
    __shared__ float p[4][NN];        // 8 KB
    __shared__ float hb[8][4][32];    // 4 KB
    __shared__ float red[4];
    __shared__ float rsv[4];

    const int t    = threadIdx.x;
    const int w    = t >> 6;
    const int lane = t & 63;

    // global Frobenius norm from 1024 partials
    float v = (partials[t] + partials[t + 256]) +
              (partials[t + 512] + partials[t + 768]);
#pragma unroll
    for (int off = 32; off; off >>= 1) v += __shfl_down(v, off);
    if (lane == 0) red[w] = v;
    __syncthreads();
    const float inv_norm = 1.0f / sqrtf((red[0] + red[1]) + (red[2] + red[3]));

    const int g0  = (blockIdx.x & 255) * 4;
    const int oq  = blockIdx.x >> 8;          // 0..3 o-quarter
    const int row = g0 + w;

    // --- softmax: wave w owns row w (8 elems/lane, pure shfl_xor) ---
    const float4* er4 = (const float4*)(e_buf + (size_t)row * NN);
    const int4*   ad4 = (const int4*)(adj + (size_t)row * NN);
    const float4 ea = er4[lane],     eb = er4[lane + 64];
    const int4   aa = ad4[lane],     ab = ad4[lane + 64];

    float va[8];
    va[0] = aa.x ? ea.x * inv_norm : -INFINITY;
    va[1] = aa.y ? ea.y * inv_norm : -INFINITY;
    va[2] = aa.z ? ea.z * inv_norm : -INFINITY;
    va[3] = aa.w ? ea.w * inv_norm : -INFINITY;
    va[4] = ab.x ? eb.x * inv_norm : -INFINITY;
    va[5] = ab.y ? eb.y * inv_norm : -INFINITY;
    va[6] = ab.z ? eb.z * inv_norm : -INFINITY;
    va[7] = ab.w ? eb.w * inv_norm : -INFINITY;

    float mx = va[0];
#pragma unroll
    for (int c = 1; c < 8; ++c) mx = fmaxf(mx, va[c]);
#pragma unroll
    for (int off = 32; off; off >>= 1) mx = fmaxf(mx, __shfl_xor(mx, off));

    float pv[8], sum = 0.f;
#pragma unroll
    for (int c = 0; c < 8; ++c) { pv[c] = expf(va[c] - mx); sum += pv[c]; }
    float4 pa = {pv[0], pv[1], pv[2], pv[3]};
    float4 pb = {pv[4], pv[5], pv[6], pv[7]};
    ((float4*)&p[w][0])[lane]      = pa;
    ((float4*)&p[w][0])[lane + 64] = pb;

#pragma unroll
    for (int off = 32; off; off >>= 1) sum += __shfl_xor(sum, off);
    if (lane == 0) rsv[w] = 1.0f / sum;
    __syncthreads();

    // --- PV: o = oq*32 + (lane&31); j-chunk jc = w*2 + (lane>>5), 64 j's ---
    const int oo = lane & 31;
    const int o  = oq * 32 + oo;
    const int jc = (w << 1) | (lane >> 5);
    const int b  = g0 >> 9;
    const float* whb = Wh + (size_t)(b * NN) * FOUT;
    const int j0 = jc * 64;

    float acc0 = 0.f, acc1 = 0.f, acc2 = 0.f, acc3 = 0.f;
    for (int j = j0; j < j0 + 64; j += 4) {
        const float4 p0 = *(const float4*)&p[0][j];
        const float4 p1 = *(const float4*)&p[1][j];
        const float4 p2 = *(const float4*)&p[2][j];
        const float4 p3 = *(const float4*)&p[3][j];
        float wv;
        wv = whb[(size_t)(j + 0) * FOUT + o];
        acc0 = fmaf(p0.x, wv, acc0); acc1 = fmaf(p1.x, wv, acc1);
        acc2 = fmaf(p2.x, wv, acc2); acc3 = fmaf(p3.x, wv, acc3);
        wv = whb[(size_t)(j + 1) * FOUT + o];
        acc0 = fmaf(p0.y, wv, acc0); acc1 = fmaf(p1.y, wv, acc1);
        acc2 = fmaf(p2.y, wv, acc2); acc3 = fmaf(p3.y, wv, acc3);
        wv = whb[(size_t)(j + 2) * FOUT + o];
        acc0 = fmaf(p0.z, wv, acc0); acc1 = fmaf(p1.z, wv, acc1);
        acc2 = fmaf(p2.z, wv, acc2); acc3 = fmaf(p3.z, wv, acc3);
        wv = whb[(size_t)(j + 3) * FOUT + o];
        acc0 = fmaf(p0.w, wv, acc0); acc1 = fmaf(p1.w, wv, acc1);
        acc2 = fmaf(p2.w, wv, acc2); acc3 = fmaf(p3.w, wv, acc3);
    }

    hb[jc][0][oo] = acc0;
    hb[jc][1][oo] = acc1;
    hb[jc][2][oo] = acc2;
    hb[jc][3][oo] = acc3;
    __syncthreads();

    if (t < 128) {
        const int r  = t >> 5;     // row 0..3
        const int o2 = t & 31;
        float h = ((hb[0][r][o2] + hb[1][r][o2]) + (hb[2][r][o2] + hb[3][r][o2])) +
                  ((hb[4][r][o2] + hb[5][r][o2]) + (hb[6][r][o2] + hb[7][r][o2]));
        h *= rsv[r];
        out[(size_t)(g0 + r) * FOUT + oq * 32 + o2] = (h > 0.f) ? h : expm1f(h);
    }
}

// ---------------------------------------------------------------------------
extern "C" void kernel_launch(void* const* d_in, const int* in_sizes, int n_in,
                              void* d_out, int out_size, void* d_ws, size_t ws_size,
                              hipStream_t stream) {
    const float* x    = (const float*)d_in[0];
    const int*   adj  = (const int*)d_in[1];
    const float* W    = (const float*)d_in[2];
    const float* a_fc = (const float*)d_in[3];
    float* out = (float*)d_out;

    float* ws       = (float*)d_ws;
    float* Wh       = ws;                         // 131072 floats
    float* u        = ws + 131072;                // 1024
    float* partials = ws + 131072 + 1024;         // 1024
    float* e_buf    = ws + 131072 + 2048;         // 524288

    wh_u_kernel<<<dim3(BB * NN / 2), dim3(256), 0, stream>>>(x, W, a_fc, Wh, u);
    e_kernel<<<dim3(NN / 16, NN / 32, BB), dim3(256), 0, stream>>>(Wh, u, a_fc, e_buf, partials);
    softmax_pv_kernel<<<dim3(1024), dim3(256), 0, stream>>>(e_buf, adj, Wh, partials, out);
}

// Round 10
// 24.629 us; speedup vs baseline: 1.7476x; 1.0255x over previous
//
#include <hip/hip_runtime.h>
#include <math.h>

constexpr int BB   = 2;
constexpr int NN   = 512;
constexpr int FIN  = 256;
constexpr int FOUT = 128;

// ---------------------------------------------------------------------------
// Kernel A: Wh = x@W, u half-dots.
// NEW: 2D grid 512 blocks = (256 row-groups of 4) x (2 o-halves of 64) x
// 256 thr. Each block reads only its 64KB W slice -> W L2 traffic 32MB
// (was 64MB). 4-row register blocking: each W float4 feeds 16 fma.
// u2[oh*1024 + row] = dot(a[oh-half], Wh[row, oh-half]); B sums the halves.
// ---------------------------------------------------------------------------
__global__ __launch_bounds__(256) void wh_u_kernel(const float* __restrict__ x,
                                                   const float* __restrict__ W,
                                                   const float* __restrict__ a_fc,
                                                   float* __restrict__ Wh,
                                                   float* __restrict__ u2) {
    __shared__ float  xs[4 * FIN];         // 4 KB
    __shared__ float4 part[4][16][17];     // 17.4 KB (pad 17: combine 2-way)

    const int t  = threadIdx.x;
    const int rg = blockIdx.x & 255;       // row group (4 rows)
    const int oh = blockIdx.x >> 8;        // o-half 0..1
    const int g0 = rg * 4;                 // global row (b*N+n flattened)

    ((float4*)xs)[t] = ((const float4*)(x + (size_t)g0 * FIN))[t];
    __syncthreads();

    const int og = t & 15;                 // o-quad within half
    const int fs = t >> 4;                 // f-slice 0..15 (16 f each)
    const float* xr = xs + fs * 16;
    const float4* W4 = (const float4*)W;
    const int ob = oh * 16 + og;           // absolute o-quad

    float4 a0 = {0.f,0.f,0.f,0.f}, a1 = {0.f,0.f,0.f,0.f};
    float4 a2 = {0.f,0.f,0.f,0.f}, a3 = {0.f,0.f,0.f,0.f};
#pragma unroll
    for (int f = 0; f < 16; ++f) {
        const float4 wv = W4[(size_t)(fs * 16 + f) * 32 + ob];
        const float v0 = xr[f];
        const float v1 = xr[FIN + f];
        const float v2 = xr[2 * FIN + f];
        const float v3 = xr[3 * FIN + f];
        a0.x = fmaf(v0, wv.x, a0.x); a1.x = fmaf(v1, wv.x, a1.x);
        a2.x = fmaf(v2, wv.x, a2.x); a3.x = fmaf(v3, wv.x, a3.x);
        a0.y = fmaf(v0, wv.y, a0.y); a1.y = fmaf(v1, wv.y, a1.y);
        a2.y = fmaf(v2, wv.y, a2.y); a3.y = fmaf(v3, wv.y, a3.y);
        a0.z = fmaf(v0, wv.z, a0.z); a1.z = fmaf(v1, wv.z, a1.z);
        a2.z = fmaf(v2, wv.z, a2.z); a3.z = fmaf(v3, wv.z, a3.z);
        a0.w = fmaf(v0, wv.w, a0.w); a1.w = fmaf(v1, wv.w, a1.w);
        a2.w = fmaf(v2, wv.w, a2.w); a3.w = fmaf(v3, wv.w, a3.w);
    }
    part[0][fs][og] = a0;
    part[1][fs][og] = a1;
    part[2][fs][og] = a2;
    part[3][fs][og] = a3;
    __syncthreads();

    if (t < 64) {
        const int rl = t >> 4;             // row 0..3 (16-lane groups)
        const int o4 = t & 15;
        float4 s = {0.f, 0.f, 0.f, 0.f};
#pragma unroll
        for (int k = 0; k < 16; ++k) {
            const float4 pk = part[rl][k][o4];
            s.x += pk.x; s.y += pk.y; s.z += pk.z; s.w += pk.w;
        }
        ((float4*)(Wh + (size_t)(g0 + rl) * FOUT))[oh * 16 + o4] = s;

        const float4 a4 = ((const float4*)a_fc)[oh * 16 + o4];
        float pa = s.x * a4.x + s.y * a4.y + s.z * a4.z + s.w * a4.w;
        pa += __shfl_down(pa, 8, 16);
        pa += __shfl_down(pa, 4, 16);
        pa += __shfl_down(pa, 2, 16);
        pa += __shfl_down(pa, 1, 16);
        if (o4 == 0) u2[(size_t)oh * 1024 + g0 + rl] = pa;
    }
}

// ---------------------------------------------------------------------------
// Kernel B: e + sumsq partials.  (FROZEN R8 winner; only u staging now sums
// the two o-half partials.)  tile 32i x 16j, grid (32,16,2), 256 thr.
// ---------------------------------------------------------------------------
__global__ __launch_bounds__(256) void e_kernel(const float* __restrict__ Wh,
                                                const float* __restrict__ u2,
                                                const float* __restrict__ a_fc,
                                                float* __restrict__ e_buf,
                                                float* __restrict__ partials) {
    __shared__ float whi[32][132];
    __shared__ float whj[16][132];
    __shared__ float a2[FOUT];
    __shared__ float usi[32];
    __shared__ float usj[16];
    __shared__ float parts[16][4][33];
    __shared__ float red[4];

    const int t   = threadIdx.x;
    const int bj0 = blockIdx.x * 16;
    const int bi0 = blockIdx.y * 32;
    const int b   = blockIdx.z;
    const float* whb = Wh + (size_t)(b * NN) * FOUT;

#pragma unroll
    for (int it = 0; it < 4; ++it) {
        const int idx = it * 256 + t;
        const int row = idx >> 5, c4 = idx & 31;
        *(float4*)&whi[row][c4 * 4] =
            *(const float4*)(whb + (size_t)(bi0 + row) * FOUT + c4 * 4);
    }
#pragma unroll
    for (int it = 0; it < 2; ++it) {
        const int idx = it * 256 + t;
        const int row = idx >> 5, c4 = idx & 31;
        *(float4*)&whj[row][c4 * 4] =
            *(const float4*)(whb + (size_t)(bj0 + row) * FOUT + c4 * 4);
    }
    if (t < 32)
        usi[t] = u2[b * NN + bi0 + t] + u2[1024 + b * NN + bi0 + t];
    else if (t < 48)
        usj[t - 32] = u2[b * NN + bj0 + (t - 32)] +
                      u2[1024 + b * NN + bj0 + (t - 32)];
    else if (t >= 128)
        a2[t - 128] = 0.4f * a_fc[t - 128];
    __syncthreads();

    const int w    = t >> 6;
    const int lane = t & 63;
    const int i    = lane & 31;
    const int jh   = lane >> 5;
    const int ob   = w * 32;

    float4 iv[8], av[8];
#pragma unroll
    for (int k = 0; k < 8; ++k) {
        iv[k] = *(const float4*)&whi[i][ob + 4 * k];
        av[k] = *(const float4*)&a2[ob + 4 * k];
    }

#pragma unroll
    for (int jj = 0; jj < 8; ++jj) {
        const int j = jh * 8 + jj;
        float4 acc = {0.f, 0.f, 0.f, 0.f};
#pragma unroll
        for (int k = 0; k < 8; ++k) {
            const float4 jv = *(const float4*)&whj[j][ob + 4 * k];
            float s;
            s = iv[k].x + jv.x; acc.x = fmaf(av[k].x, fabsf(s), acc.x);
            s = iv[k].y + jv.y; acc.y = fmaf(av[k].y, fabsf(s), acc.y);
            s = iv[k].z + jv.z; acc.z = fmaf(av[k].z, fabsf(s), acc.z);
            s = iv[k].w + jv.w; acc.w = fmaf(av[k].w, fabsf(s), acc.w);
        }
        parts[j][w][i] = (acc.x + acc.y) + (acc.z + acc.w);
    }
    __syncthreads();

    const int ci = t >> 3;
    const int jp = (t & 7) * 2;
    const float ui = usi[ci];

    const float S0 = (parts[jp][0][ci] + parts[jp][1][ci]) +
                     (parts[jp][2][ci] + parts[jp][3][ci]);
    const float v0 = fmaf(0.6f, ui + usj[jp], S0);
    const float S1 = (parts[jp + 1][0][ci] + parts[jp + 1][1][ci]) +
                     (parts[jp + 1][2][ci] + parts[jp + 1][3][ci]);
    const float v1 = fmaf(0.6f, ui + usj[jp + 1], S1);
    float ss = fmaf(v0, v0, v1 * v1);

    float2 e2 = {v0, v1};
    *(float2*)&e_buf[(size_t)(b * NN + bi0 + ci) * NN + bj0 + jp] = e2;

#pragma unroll
    for (int off = 32; off; off >>= 1) ss += __shfl_down(ss, off);
    if ((t & 63) == 0) red[t >> 6] = ss;
    __syncthreads();
    if (t == 0)
        partials[(blockIdx.z * 16 + blockIdx.y) * 32 + blockIdx.x] =
            (red[0] + red[1]) + (red[2] + red[3]);
}

// ---------------------------------------------------------------------------
// Kernel C: norm -> mask -> softmax -> att@Wh -> elu  (FROZEN R9 winner)
// 1024 blocks x 256 thr: (4 rows) x (32-o quarter), 4 blocks/CU.
// ---------------------------------------------------------------------------
__global__ __launch_bounds__(256) void softmax_pv_kernel(
        const float* __restrict__ e_buf, const int* __restrict__ adj,
        const float* __restrict__ Wh, const float* __restrict__ partials,
        float* __restrict__ out) {
    __shared__ float p[4][NN];
    __shared__ float hb[8][4][32];
    __shared__ float red[4];
    __shared__ float rsv[4];

    const int t    = threadIdx.x;
    const int w    = t >> 6;
    const int lane = t & 63;

    float v = (partials[t] + partials[t + 256]) +
              (partials[t + 512] + partials[t + 768]);
#pragma unroll
    for (int off = 32; off; off >>= 1) v += __shfl_down(v, off);
    if (lane == 0) red[w] = v;
    __syncthreads();
    const float inv_norm = 1.0f / sqrtf((red[0] + red[1]) + (red[2] + red[3]));

    const int g0  = (blockIdx.x & 255) * 4;
    const int oq  = blockIdx.x >> 8;
    const int row = g0 + w;

    const float4* er4 = (const float4*)(e_buf + (size_t)row * NN);
    const int4*   ad4 = (const int4*)(adj + (size_t)row * NN);
    const float4 ea = er4[lane],     eb = er4[lane + 64];
    const int4   aa = ad4[lane],     ab = ad4[lane + 64];

    float va[8];
    va[0] = aa.x ? ea.x * inv_norm : -INFINITY;
    va[1] = aa.y ? ea.y * inv_norm : -INFINITY;
    va[2] = aa.z ? ea.z * inv_norm : -INFINITY;
    va[3] = aa.w ? ea.w * inv_norm : -INFINITY;
    va[4] = ab.x ? eb.x * inv_norm : -INFINITY;
    va[5] = ab.y ? eb.y * inv_norm : -INFINITY;
    va[6] = ab.z ? eb.z * inv_norm : -INFINITY;
    va[7] = ab.w ? eb.w * inv_norm : -INFINITY;

    float mx = va[0];
#pragma unroll
    for (int c = 1; c < 8; ++c) mx = fmaxf(mx, va[c]);
#pragma unroll
    for (int off = 32; off; off >>= 1) mx = fmaxf(mx, __shfl_xor(mx, off));

    float pv[8], sum = 0.f;
#pragma unroll
    for (int c = 0; c < 8; ++c) { pv[c] = expf(va[c] - mx); sum += pv[c]; }
    float4 pa = {pv[0], pv[1], pv[2], pv[3]};
    float4 pb = {pv[4], pv[5], pv[6], pv[7]};
    ((float4*)&p[w][0])[lane]      = pa;
    ((float4*)&p[w][0])[lane + 64] = pb;

#pragma unroll
    for (int off = 32; off; off >>= 1) sum += __shfl_xor(sum, off);
    if (lane == 0) rsv[w] = 1.0f / sum;
    __syncthreads();

    const int oo = lane & 31;
    const int o  = oq * 32 + oo;
    const int jc = (w << 1) | (lane >> 5);
    const int b  = g0 >> 9;
    const float* whb = Wh + (size_t)(b * NN) * FOUT;
    const int j0 = jc * 64;

    float acc0 = 0.f, acc1 = 0.f, acc2 = 0.f, acc3 = 0.f;
    for (int j = j0; j < j0 + 64; j += 4) {
        const float4 p0 = *(const float4*)&p[0][j];
        const float4 p1 = *(const float4*)&p[1][j];
        const float4 p2 = *(const float4*)&p[2][j];
        const float4 p3 = *(const float4*)&p[3][j];
        float wv;
        wv = whb[(size_t)(j + 0) * FOUT + o];
        acc0 = fmaf(p0.x, wv, acc0); acc1 = fmaf(p1.x, wv, acc1);
        acc2 = fmaf(p2.x, wv, acc2); acc3 = fmaf(p3.x, wv, acc3);
        wv = whb[(size_t)(j + 1) * FOUT + o];
        acc0 = fmaf(p0.y, wv, acc0); acc1 = fmaf(p1.y, wv, acc1);
        acc2 = fmaf(p2.y, wv, acc2); acc3 = fmaf(p3.y, wv, acc3);
        wv = whb[(size_t)(j + 2) * FOUT + o];
        acc0 = fmaf(p0.z, wv, acc0); acc1 = fmaf(p1.z, wv, acc1);
        acc2 = fmaf(p2.z, wv, acc2); acc3 = fmaf(p3.z, wv, acc3);
        wv = whb[(size_t)(j + 3) * FOUT + o];
        acc0 = fmaf(p0.w, wv, acc0); acc1 = fmaf(p1.w, wv, acc1);
        acc2 = fmaf(p2.w, wv, acc2); acc3 = fmaf(p3.w, wv, acc3);
    }

    hb[jc][0][oo] = acc0;
    hb[jc][1][oo] = acc1;
    hb[jc][2][oo] = acc2;
    hb[jc][3][oo] = acc3;
    __syncthreads();

    if (t < 128) {
        const int r  = t >> 5;
        const int o2 = t & 31;
        float h = ((hb[0][r][o2] + hb[1][r][o2]) + (hb[2][r][o2] + hb[3][r][o2])) +
                  ((hb[4][r][o2] + hb[5][r][o2]) + (hb[6][r][o2] + hb[7][r][o2]));
        h *= rsv[r];
        out[(size_t)(g0 + r) * FOUT + oq * 32 + o2] = (h > 0.f) ? h : expm1f(h);
    }
}

// ---------------------------------------------------------------------------
extern "C" void kernel_launch(void* const* d_in, const int* in_sizes, int n_in,
                              void* d_out, int out_size, void* d_ws, size_t ws_size,
                              hipStream_t stream) {
    const float* x    = (const float*)d_in[0];
    const int*   adj  = (const int*)d_in[1];
    const float* W    = (const float*)d_in[2];
    const float* a_fc = (const float*)d_in[3];
    float* out = (float*)d_out;

    float* ws       = (float*)d_ws;
    float* Wh       = ws;                         // 131072 floats
    float* u2       = ws + 131072;                // 2048 (2 o-halves x 1024)
    float* partials = ws + 131072 + 2048;         // 1024
    float* e_buf    = ws + 131072 + 2048 + 1024;  // 524288

    wh_u_kernel<<<dim3(512), dim3(256), 0, stream>>>(x, W, a_fc, Wh, u2);
    e_kernel<<<dim3(NN / 16, NN / 32, BB), dim3(256), 0, stream>>>(Wh, u2, a_fc, e_buf, partials);
    softmax_pv_kernel<<<dim3(1024), dim3(256), 0, stream>>>(e_buf, adj, Wh, partials, out);
}

// Round 11
// 23.546 us; speedup vs baseline: 1.8280x; 1.0460x over previous
//
#include <hip/hip_runtime.h>
#include <math.h>

constexpr int BB   = 2;
constexpr int NN   = 512;
constexpr int FIN  = 256;
constexpr int FOUT = 128;

// ---------------------------------------------------------------------------
// Kernel A: Wh = x@W, u half-dots.  (FROZEN R10 winner)
// 512 blocks = (256 row-groups of 4) x (2 o-halves) x 256 thr.
// ---------------------------------------------------------------------------
__global__ __launch_bounds__(256) void wh_u_kernel(const float* __restrict__ x,
                                                   const float* __restrict__ W,
                                                   const float* __restrict__ a_fc,
                                                   float* __restrict__ Wh,
                                                   float* __restrict__ u2) {
    __shared__ float  xs[4 * FIN];
    __shared__ float4 part[4][16][17];

    const int t  = threadIdx.x;
    const int rg = blockIdx.x & 255;
    const int oh = blockIdx.x >> 8;
    const int g0 = rg * 4;

    ((float4*)xs)[t] = ((const float4*)(x + (size_t)g0 * FIN))[t];
    __syncthreads();

    const int og = t & 15;
    const int fs = t >> 4;
    const float* xr = xs + fs * 16;
    const float4* W4 = (const float4*)W;
    const int ob = oh * 16 + og;

    float4 a0 = {0.f,0.f,0.f,0.f}, a1 = {0.f,0.f,0.f,0.f};
    float4 a2 = {0.f,0.f,0.f,0.f}, a3 = {0.f,0.f,0.f,0.f};
#pragma unroll
    for (int f = 0; f < 16; ++f) {
        const float4 wv = W4[(size_t)(fs * 16 + f) * 32 + ob];
        const float v0 = xr[f];
        const float v1 = xr[FIN + f];
        const float v2 = xr[2 * FIN + f];
        const float v3 = xr[3 * FIN + f];
        a0.x = fmaf(v0, wv.x, a0.x); a1.x = fmaf(v1, wv.x, a1.x);
        a2.x = fmaf(v2, wv.x, a2.x); a3.x = fmaf(v3, wv.x, a3.x);
        a0.y = fmaf(v0, wv.y, a0.y); a1.y = fmaf(v1, wv.y, a1.y);
        a2.y = fmaf(v2, wv.y, a2.y); a3.y = fmaf(v3, wv.y, a3.y);
        a0.z = fmaf(v0, wv.z, a0.z); a1.z = fmaf(v1, wv.z, a1.z);
        a2.z = fmaf(v2, wv.z, a2.z); a3.z = fmaf(v3, wv.z, a3.z);
        a0.w = fmaf(v0, wv.w, a0.w); a1.w = fmaf(v1, wv.w, a1.w);
        a2.w = fmaf(v2, wv.w, a2.w); a3.w = fmaf(v3, wv.w, a3.w);
    }
    part[0][fs][og] = a0;
    part[1][fs][og] = a1;
    part[2][fs][og] = a2;
    part[3][fs][og] = a3;
    __syncthreads();

    if (t < 64) {
        const int rl = t >> 4;
        const int o4 = t & 15;
        float4 s = {0.f, 0.f, 0.f, 0.f};
#pragma unroll
        for (int k = 0; k < 16; ++k) {
            const float4 pk = part[rl][k][o4];
            s.x += pk.x; s.y += pk.y; s.z += pk.z; s.w += pk.w;
        }
        ((float4*)(Wh + (size_t)(g0 + rl) * FOUT))[oh * 16 + o4] = s;

        const float4 a4 = ((const float4*)a_fc)[oh * 16 + o4];
        float pa = s.x * a4.x + s.y * a4.y + s.z * a4.z + s.w * a4.w;
        pa += __shfl_down(pa, 8, 16);
        pa += __shfl_down(pa, 4, 16);
        pa += __shfl_down(pa, 2, 16);
        pa += __shfl_down(pa, 1, 16);
        if (o4 == 0) u2[(size_t)oh * 1024 + g0 + rl] = pa;
    }
}

// ---------------------------------------------------------------------------
// Kernel B: e + sumsq partials, SYMMETRY v2.
// e is fully symmetric in i<->j, so compute only 16x16 tiles with J >= I:
// 528 tiles/batch x 2 = 1056 blocks x 256 thr (keeps R8's 4-blocks/CU TLP,
// per-thread inner VALU halves). Off-diagonal tiles also write the
// transposed mirror tile (bit-identical values) and weight sumsq x2.
// Tile decode: closed-form quadratic with exact fp32 boundaries + guards.
// ---------------------------------------------------------------------------
__global__ __launch_bounds__(256) void e_kernel(const float* __restrict__ Wh,
                                                const float* __restrict__ u2,
                                                const float* __restrict__ a_fc,
                                                float* __restrict__ e_buf,
                                                float* __restrict__ partials) {
    __shared__ float whi[16][132];
    __shared__ float whj[16][132];
    __shared__ float a2s[FOUT];
    __shared__ float usi[16];
    __shared__ float usj[16];
    __shared__ float parts[16][4][17];
    __shared__ float red[4];

    const int t = threadIdx.x;
    int s = blockIdx.x;
    int b = 0;
    if (s >= 528) { b = 1; s -= 528; }
    // I = largest I with P(I) <= s, P(I) = 32I - I(I-1)/2 (exact fp32 bounds)
    int I = (int)(32.5f - sqrtf(1056.25f - 2.0f * (float)s));
    int PI = 32 * I - (I * (I - 1)) / 2;
    if (s < PI)                 { --I; PI = 32 * I - (I * (I - 1)) / 2; }
    else if (s >= PI + 32 - I)  { PI += 32 - I; ++I; }
    const int J    = I + (s - PI);
    const int bi0  = I * 16, bj0 = J * 16;
    const bool mir = (J > I);

    const float* whb = Wh + (size_t)(b * NN) * FOUT;

    // stage 16 i-rows + 16 j-rows (each 512 float4), coalesced
#pragma unroll
    for (int it = 0; it < 2; ++it) {
        const int idx = it * 256 + t;
        const int row = idx >> 5, c4 = idx & 31;
        *(float4*)&whi[row][c4 * 4] =
            *(const float4*)(whb + (size_t)(bi0 + row) * FOUT + c4 * 4);
        *(float4*)&whj[row][c4 * 4] =
            *(const float4*)(whb + (size_t)(bj0 + row) * FOUT + c4 * 4);
    }
    if (t < 16)
        usi[t] = u2[b * NN + bi0 + t] + u2[1024 + b * NN + bi0 + t];
    else if (t < 32)
        usj[t - 16] = u2[b * NN + bj0 + (t - 16)] +
                      u2[1024 + b * NN + bj0 + (t - 16)];
    else if (t >= 128)
        a2s[t - 128] = 0.4f * a_fc[t - 128];
    __syncthreads();

    const int w    = t >> 6;      // o-chunk [32w, 32w+32)
    const int lane = t & 63;
    const int i    = lane & 15;   // i-row (4-lane broadcast groups)
    const int jg   = lane >> 4;   // j-group 0..3
    const int ob   = w * 32;

    float4 iv[8], av[8];
#pragma unroll
    for (int k = 0; k < 8; ++k) {
        iv[k] = *(const float4*)&whi[i][ob + 4 * k];
        av[k] = *(const float4*)&a2s[ob + 4 * k];
    }

#pragma unroll
    for (int jj = 0; jj < 4; ++jj) {
        const int j = jg * 4 + jj;
        float4 acc = {0.f, 0.f, 0.f, 0.f};
#pragma unroll
        for (int k = 0; k < 8; ++k) {
            const float4 jv = *(const float4*)&whj[j][ob + 4 * k];
            float sv;
            sv = iv[k].x + jv.x; acc.x = fmaf(av[k].x, fabsf(sv), acc.x);
            sv = iv[k].y + jv.y; acc.y = fmaf(av[k].y, fabsf(sv), acc.y);
            sv = iv[k].z + jv.z; acc.z = fmaf(av[k].z, fabsf(sv), acc.z);
            sv = iv[k].w + jv.w; acc.w = fmaf(av[k].w, fabsf(sv), acc.w);
        }
        parts[j][w][i] = (acc.x + acc.y) + (acc.z + acc.w);
    }
    __syncthreads();

    // combine: 1 cell/thread  (ci = t>>4, cj = t&15)
    const int ci = t >> 4;
    const int cj = t & 15;
    const float S = (parts[cj][0][ci] + parts[cj][1][ci]) +
                    (parts[cj][2][ci] + parts[cj][3][ci]);
    const float v = fmaf(0.6f, usi[ci] + usj[cj], S);
    float ss = v * v;
    e_buf[(size_t)(b * NN + bi0 + ci) * NN + bj0 + cj] = v;
    if (mir) {
        e_buf[(size_t)(b * NN + bj0 + cj) * NN + bi0 + ci] = v;
        ss += ss;   // mirror cell contributes the same v^2 once
    }

#pragma unroll
    for (int off = 32; off; off >>= 1) ss += __shfl_down(ss, off);
    if ((t & 63) == 0) red[t >> 6] = ss;
    __syncthreads();
    if (t == 0)
        partials[blockIdx.x] = (red[0] + red[1]) + (red[2] + red[3]);
}

// ---------------------------------------------------------------------------
// Kernel C: norm -> mask -> softmax -> att@Wh -> elu  (FROZEN R9/R10 winner;
// partials reduce widened to 1056 entries)
// 1024 blocks x 256 thr: (4 rows) x (32-o quarter), 4 blocks/CU.
// ---------------------------------------------------------------------------
__global__ __launch_bounds__(256) void softmax_pv_kernel(
        const float* __restrict__ e_buf, const int* __restrict__ adj,
        const float* __restrict__ Wh, const float* __restrict__ partials,
        float* __restrict__ out) {
    __shared__ float p[4][NN];
    __shared__ float hb[8][4][32];
    __shared__ float red[4];
    __shared__ float rsv[4];

    const int t    = threadIdx.x;
    const int w    = t >> 6;
    const int lane = t & 63;

    // global Frobenius norm from 1056 partials
    float v = (partials[t] + partials[t + 256]) +
              (partials[t + 512] + partials[t + 768]);
    if (t < 32) v += partials[t + 1024];
#pragma unroll
    for (int off = 32; off; off >>= 1) v += __shfl_down(v, off);
    if (lane == 0) red[w] = v;
    __syncthreads();
    const float inv_norm = 1.0f / sqrtf((red[0] + red[1]) + (red[2] + red[3]));

    const int g0  = (blockIdx.x & 255) * 4;
    const int oq  = blockIdx.x >> 8;
    const int row = g0 + w;

    const float4* er4 = (const float4*)(e_buf + (size_t)row * NN);
    const int4*   ad4 = (const int4*)(adj + (size_t)row * NN);
    const float4 ea = er4[lane],     eb = er4[lane + 64];
    const int4   aa = ad4[lane],     ab = ad4[lane + 64];

    float va[8];
    va[0] = aa.x ? ea.x * inv_norm : -INFINITY;
    va[1] = aa.y ? ea.y * inv_norm : -INFINITY;
    va[2] = aa.z ? ea.z * inv_norm : -INFINITY;
    va[3] = aa.w ? ea.w * inv_norm : -INFINITY;
    va[4] = ab.x ? eb.x * inv_norm : -INFINITY;
    va[5] = ab.y ? eb.y * inv_norm : -INFINITY;
    va[6] = ab.z ? eb.z * inv_norm : -INFINITY;
    va[7] = ab.w ? eb.w * inv_norm : -INFINITY;

    float mx = va[0];
#pragma unroll
    for (int c = 1; c < 8; ++c) mx = fmaxf(mx, va[c]);
#pragma unroll
    for (int off = 32; off; off >>= 1) mx = fmaxf(mx, __shfl_xor(mx, off));

    float pv[8], sum = 0.f;
#pragma unroll
    for (int c = 0; c < 8; ++c) { pv[c] = expf(va[c] - mx); sum += pv[c]; }
    float4 pa = {pv[0], pv[1], pv[2], pv[3]};
    float4 pb = {pv[4], pv[5], pv[6], pv[7]};
    ((float4*)&p[w][0])[lane]      = pa;
    ((float4*)&p[w][0])[lane + 64] = pb;

#pragma unroll
    for (int off = 32; off; off >>= 1) sum += __shfl_xor(sum, off);
    if (lane == 0) rsv[w] = 1.0f / sum;
    __syncthreads();

    const int oo = lane & 31;
    const int o  = oq * 32 + oo;
    const int jc = (w << 1) | (lane >> 5);
    const int b  = g0 >> 9;
    const float* whb = Wh + (size_t)(b * NN) * FOUT;
    const int j0 = jc * 64;

    float acc0 = 0.f, acc1 = 0.f, acc2 = 0.f, acc3 = 0.f;
    for (int j = j0; j < j0 + 64; j += 4) {
        const float4 p0 = *(const float4*)&p[0][j];
        const float4 p1 = *(const float4*)&p[1][j];
        const float4 p2 = *(const float4*)&p[2][j];
        const float4 p3 = *(const float4*)&p[3][j];
        float wv;
        wv = whb[(size_t)(j + 0) * FOUT + o];
        acc0 = fmaf(p0.x, wv, acc0); acc1 = fmaf(p1.x, wv, acc1);
        acc2 = fmaf(p2.x, wv, acc2); acc3 = fmaf(p3.x, wv, acc3);
        wv = whb[(size_t)(j + 1) * FOUT + o];
        acc0 = fmaf(p0.y, wv, acc0); acc1 = fmaf(p1.y, wv, acc1);
        acc2 = fmaf(p2.y, wv, acc2); acc3 = fmaf(p3.y, wv, acc3);
        wv = whb[(size_t)(j + 2) * FOUT + o];
        acc0 = fmaf(p0.z, wv, acc0); acc1 = fmaf(p1.z, wv, acc1);
        acc2 = fmaf(p2.z, wv, acc2); acc3 = fmaf(p3.z, wv, acc3);
        wv = whb[(size_t)(j + 3) * FOUT + o];
        acc0 = fmaf(p0.w, wv, acc0); acc1 = fmaf(p1.w, wv, acc1);
        acc2 = fmaf(p2.w, wv, acc2); acc3 = fmaf(p3.w, wv, acc3);
    }

    hb[jc][0][oo] = acc0;
    hb[jc][1][oo] = acc1;
    hb[jc][2][oo] = acc2;
    hb[jc][3][oo] = acc3;
    __syncthreads();

    if (t < 128) {
        const int r  = t >> 5;
        const int o2 = t & 31;
        float h = ((hb[0][r][o2] + hb[1][r][o2]) + (hb[2][r][o2] + hb[3][r][o2])) +
                  ((hb[4][r][o2] + hb[5][r][o2]) + (hb[6][r][o2] + hb[7][r][o2]));
        h *= rsv[r];
        out[(size_t)(g0 + r) * FOUT + oq * 32 + o2] = (h > 0.f) ? h : expm1f(h);
    }
}

// ---------------------------------------------------------------------------
extern "C" void kernel_launch(void* const* d_in, const int* in_sizes, int n_in,
                              void* d_out, int out_size, void* d_ws, size_t ws_size,
                              hipStream_t stream) {
    const float* x    = (const float*)d_in[0];
    const int*   adj  = (const int*)d_in[1];
    const float* W    = (const float*)d_in[2];
    const float* a_fc = (const float*)d_in[3];
    float* out = (float*)d_out;

    float* ws       = (float*)d_ws;
    float* Wh       = ws;                         // 131072 floats
    float* u2       = ws + 131072;                // 2048
    float* partials = ws + 131072 + 2048;         // 1280 (1056 used)
    float* e_buf    = ws + 131072 + 2048 + 1280;  // 524288

    wh_u_kernel<<<dim3(512), dim3(256), 0, stream>>>(x, W, a_fc, Wh, u2);
    e_kernel<<<dim3(1056), dim3(256), 0, stream>>>(Wh, u2, a_fc, e_buf, partials);
    softmax_pv_kernel<<<dim3(1024), dim3(256), 0, stream>>>(e_buf, adj, Wh, partials, out);
}